// Round 1
// baseline (920.922 us; speedup 1.0000x reference)
//
#include <hip/hip_runtime.h>
#include <stdint.h>

#define VHW 98304
#define MAXID_C 8192

__device__ __forceinline__ unsigned fkey(float f){
  unsigned u = __float_as_uint(f);
  return (u & 0x80000000u) ? ~u : (u | 0x80000000u);
}
__device__ __forceinline__ float fval(unsigned k){
  unsigned u = (k & 0x80000000u) ? (k & 0x7fffffffu) : ~k;
  return __uint_as_float(u);
}

struct Ptrs { const float* p[11]; };

// ---- init per-segment state (ws is re-poisoned to 0xAA before every call) ----
__global__ void k_init(float* __restrict__ sums, float* __restrict__ c1num,
                       float* __restrict__ d1, float* __restrict__ d2,
                       int* __restrict__ cnt, unsigned* __restrict__ mx1,
                       unsigned* __restrict__ mx2, int* __restrict__ minidx, int S){
  int t = blockIdx.x*blockDim.x + threadIdx.x;
  if (t < 106*S) sums[t] = 0.f;
  if (t < 3*S)  c1num[t] = 0.f;
  if (t < S){ d1[t]=0.f; d2[t]=0.f; cnt[t]=0; mx1[t]=0u; mx2[t]=0u; minidx[t]=0x7fffffff; }
}

// ---- pass 1: seg ids, counts, segment max of keep0 over valid ----
__global__ void k_p1(const int* __restrict__ ids, const float* __restrict__ keep,
                     int* __restrict__ segarr, int* __restrict__ cnt,
                     unsigned* __restrict__ mx1, int M){
  int i = blockIdx.x*blockDim.x + threadIdx.x;
  if (i >= M) return;
  int id = ids[i];
  if (id < 0){ segarr[i] = -1; return; }
  int seg = (i / VHW) * MAXID_C + id;
  segarr[i] = seg;
  atomicAdd(&cnt[seg], 1);
  atomicMax(&mx1[seg], fkey(keep[i]));
}

// ---- pass 2: softmax-1 denom + weighted-center numerator ----
__global__ void k_p2(const int* __restrict__ segarr, const float* __restrict__ keep,
                     const float* __restrict__ center, const unsigned* __restrict__ mx1,
                     float* __restrict__ d1, float* __restrict__ c1num, int M){
  int i = blockIdx.x*blockDim.x + threadIdx.x;
  if (i >= M) return;
  int seg = segarr[i];
  if (seg < 0) return;
  float e1 = expf(keep[i] - fval(mx1[seg]));
  atomicAdd(&d1[seg], e1);
  atomicAdd(&c1num[seg*3+0], center[i*3+0]*e1);
  atomicAdd(&c1num[seg*3+1], center[i*3+1]*e1);
  atomicAdd(&c1num[seg*3+2], center[i*3+2]*e1);
}

// ---- pass 3: distance gate -> active, segment max over active ----
__global__ void k_p3(const int* __restrict__ segarr, const float* __restrict__ keep,
                     const float* __restrict__ center, const int* __restrict__ cnt,
                     const float* __restrict__ d1, const float* __restrict__ c1num,
                     unsigned* __restrict__ mx2, uint8_t* __restrict__ active, int M){
  int i = blockIdx.x*blockDim.x + threadIdx.x;
  if (i >= M) return;
  int seg = segarr[i];
  uint8_t act = 0;
  if (seg >= 0 && cnt[seg] >= 2){
    float inv = 1.f / d1[seg];
    float dx = center[i*3+0] - c1num[seg*3+0]*inv;
    float dy = center[i*3+1] - c1num[seg*3+1]*inv;
    float dz = center[i*3+2] - c1num[seg*3+2]*inv;
    float dist = sqrtf(dx*dx + dy*dy + dz*dz);
    if (dist <= 2.0f){
      act = 1;
      atomicMax(&mx2[seg], fkey(keep[i]));
    }
  }
  active[i] = act;
}

// ---- pass 4a: softmax-2 weights, denom, representative (min idx among argmax) ----
__global__ void k_p4a(const int* __restrict__ segarr, const float* __restrict__ keep,
                      const uint8_t* __restrict__ active, const unsigned* __restrict__ mx2,
                      float* __restrict__ e2arr, float* __restrict__ d2,
                      int* __restrict__ minidx, int M){
  int i = blockIdx.x*blockDim.x + threadIdx.x;
  if (i >= M) return;
  if (!active[i]) return;
  int seg = segarr[i];
  float k0 = keep[i];
  float m  = fval(mx2[seg]);
  float e2 = expf(k0 - m);
  e2arr[i] = e2;
  atomicAdd(&d2[seg], e2);
  if (k0 >= m) atomicMin(&minidx[seg], i);
}

// ---- pass 4b: 106-channel weighted sums (flat over 106*M) ----
__global__ void k_p4b(Ptrs in, const int* __restrict__ segarr,
                      const uint8_t* __restrict__ active, const float* __restrict__ e2arr,
                      float* __restrict__ sums, int M){
  unsigned j = blockIdx.x*blockDim.x + threadIdx.x;
  unsigned uM = (unsigned)M;
  unsigned total = 106u*uM;
  if (j >= total) return;
  // regions exclude keep_score (handled via mx2); sums base == roff
  const int roff[11] = {0,64,67,70,71,74,78,81,97,105,106};
  const int rC[10]   = {64,3,3,1,3,4,3,16,8,1};
  const int rin[10]  = {0,1,2,3,4,5,6,8,9,10};
  int r = 0;
  #pragma unroll
  for (int k = 1; k < 10; k++) if (j >= (unsigned)roff[k]*uM) r = k;
  unsigned local = j - (unsigned)roff[r]*uM;
  int C = rC[r];
  unsigned i, c;
  switch (C){
    case 64: i = local >> 6; c = local & 63u; break;
    case 16: i = local >> 4; c = local & 15u; break;
    case 8:  i = local >> 3; c = local & 7u;  break;
    case 4:  i = local >> 2; c = local & 3u;  break;
    case 3:  i = local / 3u; c = local - i*3u; break;
    default: i = local; c = 0u; break;
  }
  if (!active[i]) return;
  int seg = segarr[i];
  float x = in.p[rin[r]][(size_t)i*(unsigned)C + c];
  atomicAdd(&sums[(unsigned)seg*106u + (unsigned)roff[r] + c], x * e2arr[i]);
}

// ---- pass 5: finalize means + rotation normalize (per segment) ----
__global__ void k_p5(float* __restrict__ sums, const float* __restrict__ d2, int S){
  int s = blockIdx.x*blockDim.x + threadIdx.x;
  if (s >= S) return;
  float dv = d2[s];
  if (dv <= 0.f) return;
  float inv = 1.f / dv;
  float* p = &sums[(size_t)s*106];
  for (int c = 0; c < 106; c++) p[c] *= inv;
  float n = sqrtf(p[74]*p[74] + p[75]*p[75] + p[76]*p[76] + p[77]*p[77]);
  float rinv = 1.f / fmaxf(n, 1e-12f);
  p[74]*=rinv; p[75]*=rinv; p[76]*=rinv; p[77]*=rinv;
}

// ---- pass 6: scatter outputs (flat over 107*M, layout == d_out) ----
__global__ void k_p6(Ptrs in, float* __restrict__ out, const int* __restrict__ segarr,
                     const uint8_t* __restrict__ active, const float* __restrict__ sums,
                     const unsigned* __restrict__ mx2, const int* __restrict__ minidx, int M){
  unsigned j = blockIdx.x*blockDim.x + threadIdx.x;
  unsigned uM = (unsigned)M;
  unsigned total = 107u*uM;
  if (j >= total) return;
  const int roff[12]  = {0,64,67,70,71,74,78,81,82,98,106,107};
  const int rC[11]    = {64,3,3,1,3,4,3,1,16,8,1};
  const int sbase[11] = {0,64,67,70,71,74,78,0,81,97,105};
  int r = 0;
  #pragma unroll
  for (int k = 1; k < 11; k++) if (j >= (unsigned)roff[k]*uM) r = k;
  unsigned local = j - (unsigned)roff[r]*uM;
  int C = rC[r];
  unsigned i, c;
  switch (C){
    case 64: i = local >> 6; c = local & 63u; break;
    case 16: i = local >> 4; c = local & 15u; break;
    case 8:  i = local >> 3; c = local & 7u;  break;
    case 4:  i = local >> 2; c = local & 3u;  break;
    case 3:  i = local / 3u; c = local - i*3u; break;
    default: i = local; c = 0u; break;
  }
  float orig = in.p[r][local];
  float v;
  if (!active[i]) {
    v = orig;
  } else {
    int seg = segarr[i];
    if (r == 7){                       // keep_score: segment max * factor
      float f = (minidx[seg] == (int)i) ? 1.f : 0.05f;
      v = fval(mx2[seg]) * f;
    } else {
      v = sums[(unsigned)seg*106u + (unsigned)sbase[r] + c];
      if (r == 3){                     // opacity: mean * factor
        float f = (minidx[seg] == (int)i) ? 1.f : 0.05f;
        v *= f;
      }
    }
  }
  out[j] = v;
}

extern "C" void kernel_launch(void* const* d_in, const int* in_sizes, int n_in,
                              void* d_out, int out_size, void* d_ws, size_t ws_size,
                              hipStream_t stream) {
  Ptrs P;
  for (int k = 0; k < 11; k++) P.p[k] = (const float*)d_in[k];
  const int*   ids    = (const int*)d_in[11];
  const float* keep   = (const float*)d_in[7];
  const float* center = (const float*)d_in[1];

  int M  = in_sizes[11];
  int BT = M / VHW;
  int S  = BT * MAXID_C + 1;

  // workspace layout (all 4-byte units unless noted)
  float*    sums   = (float*)d_ws;                 // 106*S
  float*    c1num  = sums  + (size_t)106*S;        // 3*S
  float*    d1     = c1num + (size_t)3*S;          // S
  float*    d2     = d1 + S;                       // S
  int*      cnt    = (int*)(d2 + S);               // S
  unsigned* mx1    = (unsigned*)(cnt + S);         // S
  unsigned* mx2    = mx1 + S;                      // S
  int*      minidx = (int*)(mx2 + S);              // S
  int*      segarr = minidx + S;                   // M
  float*    e2arr  = (float*)(segarr + M);         // M
  uint8_t*  active = (uint8_t*)(e2arr + M);        // M bytes

  const int B = 256;
  int gi = (106*S + B - 1) / B;
  int gm = (M + B - 1) / B;
  unsigned t4 = 106u*(unsigned)M, t6 = 107u*(unsigned)M;

  k_init<<<gi, B, 0, stream>>>(sums, c1num, d1, d2, cnt, mx1, mx2, minidx, S);
  k_p1  <<<gm, B, 0, stream>>>(ids, keep, segarr, cnt, mx1, M);
  k_p2  <<<gm, B, 0, stream>>>(segarr, keep, center, mx1, d1, c1num, M);
  k_p3  <<<gm, B, 0, stream>>>(segarr, keep, center, cnt, d1, c1num, mx2, active, M);
  k_p4a <<<gm, B, 0, stream>>>(segarr, keep, active, mx2, e2arr, d2, minidx, M);
  k_p4b <<<(t4 + B - 1)/B, B, 0, stream>>>(P, segarr, active, e2arr, sums, M);
  k_p5  <<<(S + B - 1)/B, B, 0, stream>>>(sums, d2, S);
  k_p6  <<<(t6 + B - 1)/B, B, 0, stream>>>(P, (float*)d_out, segarr, active, sums, mx2, minidx, M);
}

// Round 2
// 653.396 us; speedup vs baseline: 1.4094x; 1.4094x over previous
//
#include <hip/hip_runtime.h>
#include <stdint.h>
#include <float.h>

#define VHW 98304
#define MAXID_C 8192

struct Ptrs { const float* p[11]; };

// ---- init: zero the small per-segment arrays (ws re-poisoned every call) ----
__global__ void k_init(int* __restrict__ cnt, int* __restrict__ cursor,
                       float* __restrict__ d2, int S){
  int t = blockIdx.x*blockDim.x + threadIdx.x;
  if (t < S){ cnt[t]=0; cursor[t]=0; d2[t]=0.f; }
}

// ---- pass 1: seg ids + counts ----
__global__ void k_p1(const int* __restrict__ ids, int* __restrict__ segarr,
                     int* __restrict__ cnt, int M){
  int i = blockIdx.x*blockDim.x + threadIdx.x;
  if (i >= M) return;
  int id = ids[i];
  if (id < 0){ segarr[i] = -1; return; }
  int seg = (i / VHW) * MAXID_C + id;
  segarr[i] = seg;
  atomicAdd(&cnt[seg], 1);
}

// ---- exclusive scan of cnt -> offs (single block of 1024) ----
__global__ void k_scan(const int* __restrict__ cnt, int* __restrict__ offs,
                       int S, int K){
  __shared__ int part[1024];
  int t = threadIdx.x;
  int base = t*K, sum = 0;
  for (int k = 0; k < K; k++){ int idx = base+k; if (idx < S) sum += cnt[idx]; }
  part[t] = sum; __syncthreads();
  for (int d = 1; d < 1024; d <<= 1){
    int v = (t >= d) ? part[t-d] : 0;
    __syncthreads();
    part[t] += v;
    __syncthreads();
  }
  int run = (t == 0) ? 0 : part[t-1];
  for (int k = 0; k < K; k++){
    int idx = base+k;
    if (idx < S){ offs[idx] = run; run += cnt[idx]; }
  }
}

// ---- fill per-segment element lists; zero active for invalid elements ----
__global__ void k_fill(const int* __restrict__ segarr, const int* __restrict__ offs,
                       int* __restrict__ cursor, int* __restrict__ list,
                       uint8_t* __restrict__ active, int M){
  int i = blockIdx.x*blockDim.x + threadIdx.x;
  if (i >= M) return;
  int seg = segarr[i];
  if (seg < 0){ active[i] = 0; return; }
  int pos = atomicAdd(&cursor[seg], 1);
  list[offs[seg] + pos] = i;
}

// ---- per-segment stats: mx1 -> softmax1 -> center mean -> gate -> mx2/d2/minidx
// one thread per segment, no atomics
__global__ void k_stats(const float* __restrict__ keep, const float* __restrict__ cen,
                        const int* __restrict__ list, const int* __restrict__ offs,
                        const int* __restrict__ cnt,
                        uint8_t* __restrict__ active, float* __restrict__ e2arr,
                        float* __restrict__ d2arr, float* __restrict__ mx2arr,
                        int* __restrict__ minidxarr, int S){
  int s = blockIdx.x*blockDim.x + threadIdx.x;
  if (s >= S) return;
  int n = cnt[s];
  if (n == 0) return;
  int off = offs[s];
  if (n < 2){
    for (int e = 0; e < n; e++) active[list[off+e]] = 0;
    return;
  }
  // pass 1: segment max of keep (exact, matches segment_max)
  float m1 = -FLT_MAX;
  for (int e = 0; e < n; e++) m1 = fmaxf(m1, keep[list[off+e]]);
  // pass 2: softmax-1 denom + weighted center numerator
  float d1 = 0.f, cx = 0.f, cy = 0.f, cz = 0.f;
  for (int e = 0; e < n; e++){
    int i = list[off+e];
    float e1 = expf(keep[i] - m1);
    d1 += e1;
    cx += cen[(size_t)i*3+0]*e1;
    cy += cen[(size_t)i*3+1]*e1;
    cz += cen[(size_t)i*3+2]*e1;
  }
  float inv = 1.f / d1;
  float mcx = cx*inv, mcy = cy*inv, mcz = cz*inv;
  // pass 3: distance gate -> active, segment max over active
  float m2 = -FLT_MAX; bool any = false;
  for (int e = 0; e < n; e++){
    int i = list[off+e];
    float dx = cen[(size_t)i*3+0]-mcx, dy = cen[(size_t)i*3+1]-mcy, dz = cen[(size_t)i*3+2]-mcz;
    float dist = sqrtf(dx*dx+dy*dy+dz*dz);
    uint8_t a = (dist <= 2.0f) ? 1 : 0;
    active[i] = a;
    if (a){ m2 = fmaxf(m2, keep[i]); any = true; }
  }
  if (!any) return;   // d2arr stays 0 -> p4b skips, p6 never reads
  // pass 4: softmax-2 weights + denom + representative
  float D2 = 0.f; int mi = 0x7fffffff;
  for (int e = 0; e < n; e++){
    int i = list[off+e];
    if (!active[i]) continue;
    float k0 = keep[i];
    float e2 = expf(k0 - m2);
    e2arr[i] = e2;
    D2 += e2;
    if (k0 >= m2 && i < mi) mi = i;
  }
  d2arr[s] = D2; mx2arr[s] = m2; minidxarr[s] = mi;
}

// ---- weighted means: one wave per segment, register accumulation, no atomics
__global__ void k_p4b(Ptrs in, const int* __restrict__ list, const int* __restrict__ offs,
                      const int* __restrict__ cnt, const uint8_t* __restrict__ active,
                      const float* __restrict__ e2arr, const float* __restrict__ d2arr,
                      float* __restrict__ sums, int S){
  int wid  = (blockIdx.x*blockDim.x + threadIdx.x) >> 6;
  int lane = threadIdx.x & 63;
  if (wid >= S) return;
  float dv = d2arr[wid];
  if (dv <= 0.f) return;
  // lane -> second channel (64+lane) mapping
  const float* b2 = nullptr; int C2 = 1, o2 = 0;
  if      (lane < 3) { b2 = in.p[1];  C2 = 3;  o2 = lane;      }  // center
  else if (lane < 6) { b2 = in.p[2];  C2 = 3;  o2 = lane-3;    }  // offset
  else if (lane < 7) { b2 = in.p[3];  C2 = 1;  o2 = 0;         }  // opacity
  else if (lane < 10){ b2 = in.p[4];  C2 = 3;  o2 = lane-7;    }  // scale
  else if (lane < 14){ b2 = in.p[5];  C2 = 4;  o2 = lane-10;   }  // rotation
  else if (lane < 17){ b2 = in.p[6];  C2 = 3;  o2 = lane-14;   }  // feat_dc
  else if (lane < 33){ b2 = in.p[8];  C2 = 16; o2 = lane-17;   }  // instance_affinity
  else if (lane < 41){ b2 = in.p[9];  C2 = 8;  o2 = lane-33;   }  // motion_code
  else if (lane < 42){ b2 = in.p[10]; C2 = 1;  o2 = 0;         }  // dynamic_logit
  const float* dense = in.p[0];
  int off = offs[wid], n = cnt[wid];
  float acc1 = 0.f, acc2 = 0.f;
  for (int e = 0; e < n; e++){
    int i = list[off+e];
    if (!active[i]) continue;          // wave-uniform branch
    float w = e2arr[i];
    acc1 += w * dense[(size_t)i*64 + lane];
    if (lane < 42) acc2 += w * b2[(size_t)i*C2 + o2];
  }
  float inv = 1.f/dv;
  float v1 = acc1*inv, v2 = acc2*inv;
  // rotation = channels 74..77 = lanes 10..13 of v2: normalize in-wave
  float q0 = __shfl(v2,10), q1 = __shfl(v2,11), q2 = __shfl(v2,12), q3 = __shfl(v2,13);
  float nrm = sqrtf(q0*q0+q1*q1+q2*q2+q3*q3);
  float rn  = 1.f/fmaxf(nrm, 1e-12f);
  if (lane >= 10 && lane < 14) v2 *= rn;
  float* p = &sums[(size_t)wid*106];
  p[lane] = v1;
  if (lane < 42) p[64+lane] = v2;
}

// ---- scatter outputs, float4-vectorized (all region boundaries %4 == 0) ----
__global__ void k_p6(Ptrs in, float4* __restrict__ out, const int* __restrict__ segarr,
                     const uint8_t* __restrict__ active, const float* __restrict__ sums,
                     const float* __restrict__ mx2arr, const int* __restrict__ minidx,
                     int M){
  unsigned j4 = blockIdx.x*blockDim.x + threadIdx.x;
  unsigned uM = (unsigned)M;
  unsigned total4 = (107u*uM) >> 2;
  if (j4 >= total4) return;
  unsigned j = j4 << 2;
  const int roff[12]  = {0,64,67,70,71,74,78,81,82,98,106,107};
  const int rC[11]    = {64,3,3,1,3,4,3,1,16,8,1};
  const int sbase[11] = {0,64,67,70,71,74,78,0,81,97,105};
  int r = 0;
  #pragma unroll
  for (int k = 1; k < 11; k++) if (j >= (unsigned)roff[k]*uM) r = k;
  unsigned local = j - (unsigned)roff[r]*uM;   // %4 == 0
  int C = rC[r];
  float4 orig = *(const float4*)(in.p[r] + local);
  float o[4] = {orig.x, orig.y, orig.z, orig.w};
  float res[4];
  #pragma unroll
  for (int t = 0; t < 4; t++){
    unsigned l = local + (unsigned)t;
    unsigned i, c;
    switch (C){
      case 64: i = l >> 6; c = l & 63u; break;
      case 16: i = l >> 4; c = l & 15u; break;
      case 8:  i = l >> 3; c = l & 7u;  break;
      case 4:  i = l >> 2; c = l & 3u;  break;
      case 3:  i = l / 3u; c = l - i*3u; break;
      default: i = l;      c = 0u;      break;
    }
    if (!active[i]){ res[t] = o[t]; continue; }
    int seg = segarr[i];
    if (r == 7){                              // keep_score: max * factor
      float f = (minidx[seg] == (int)i) ? 1.f : 0.05f;
      res[t] = mx2arr[seg] * f;
    } else {
      float v = sums[(unsigned)seg*106u + (unsigned)sbase[r] + c];
      if (r == 3){                            // opacity: mean * factor
        float f = (minidx[seg] == (int)i) ? 1.f : 0.05f;
        v *= f;
      }
      res[t] = v;
    }
  }
  out[j4] = make_float4(res[0], res[1], res[2], res[3]);
}

extern "C" void kernel_launch(void* const* d_in, const int* in_sizes, int n_in,
                              void* d_out, int out_size, void* d_ws, size_t ws_size,
                              hipStream_t stream) {
  Ptrs P;
  for (int k = 0; k < 11; k++) P.p[k] = (const float*)d_in[k];
  const int*   ids    = (const int*)d_in[11];
  const float* keep   = (const float*)d_in[7];
  const float* center = (const float*)d_in[1];

  int M  = in_sizes[11];
  int BT = M / VHW;
  int S  = BT * MAXID_C + 1;

  // workspace layout (4-byte units; active is bytes at the end)
  float*    sums    = (float*)d_ws;                 // 106*S
  int*      offs    = (int*)(sums + (size_t)106*S); // S
  int*      cursor  = offs + S;                     // S
  int*      cnt     = cursor + S;                   // S
  float*    d2arr   = (float*)(cnt + S);            // S
  float*    mx2arr  = d2arr + S;                    // S
  int*      minidx  = (int*)(mx2arr + S);           // S
  int*      segarr  = minidx + S;                   // M
  float*    e2arr   = (float*)(segarr + M);         // M
  int*      list    = (int*)(e2arr + M);            // M
  uint8_t*  active  = (uint8_t*)(list + M);         // M bytes

  const int B = 256;
  int gm = (M + B - 1) / B;
  int gs = (S + B - 1) / B;
  int K  = (S + 1023) / 1024;
  unsigned t6 = (107u*(unsigned)M) >> 2;

  k_init <<<gs, B, 0, stream>>>(cnt, cursor, d2arr, S);
  k_p1   <<<gm, B, 0, stream>>>(ids, segarr, cnt, M);
  k_scan <<<1, 1024, 0, stream>>>(cnt, offs, S, K);
  k_fill <<<gm, B, 0, stream>>>(segarr, offs, cursor, list, active, M);
  k_stats<<<gs, B, 0, stream>>>(keep, center, list, offs, cnt, active, e2arr,
                                d2arr, mx2arr, minidx, S);
  k_p4b  <<<(S*64 + B - 1)/B, B, 0, stream>>>(P, list, offs, cnt, active, e2arr,
                                              d2arr, sums, S);
  k_p6   <<<(t6 + B - 1)/B, B, 0, stream>>>(P, (float4*)d_out, segarr, active,
                                            sums, mx2arr, minidx, M);
}